// Round 4
// baseline (2290.416 us; speedup 1.0000x reference)
//
#include <hip/hip_runtime.h>
#include <cstdint>
#include <cstddef>

#define B_ 4
#define T_ 24
#define N_ 512

// gate nonlinearities: evaluate in f64, round once to f32 (minimizes our-side libm noise)
__device__ __forceinline__ float fsig(float x)  { return (float)(1.0 / (1.0 + exp(-(double)x))); }
__device__ __forceinline__ float ftanh(float x) { return (float)tanh((double)x); }

// ---------------- xp = relu(x @ fc_w + fc_b), f32, row-major [bt][512][64] ----------------
__global__ __launch_bounds__(256) void xp_kernel(const float* __restrict__ x,
                                                 const float* __restrict__ fc_w,
                                                 const float* __restrict__ fc_b,
                                                 float* __restrict__ xp) {
    __shared__ float sW[64 * 64];
    __shared__ float sB[64];
    __shared__ float sX[64 * 65];
    int bt = blockIdx.x;                  // 0..95
    int tid = threadIdx.x;
    for (int i = tid; i < 4096; i += 256) sW[i] = fc_w[i];
    if (tid < 64) sB[tid] = fc_b[tid];
    const float* xb = x + (size_t)bt * N_ * 64;
    float* ob = xp + (size_t)bt * N_ * 64;
    for (int rt = 0; rt < 8; ++rt) {
        __syncthreads();
        {   // stage 64 rows x 64 cols of x
            int r = tid >> 2, kq = (tid & 3) * 16;
            const float* p = xb + (size_t)(rt * 64 + r) * 64 + kq;
            #pragma unroll
            for (int i = 0; i < 4; ++i) {
                float4 d = *(const float4*)(p + i * 4);
                sX[r * 65 + kq + i * 4 + 0] = d.x;
                sX[r * 65 + kq + i * 4 + 1] = d.y;
                sX[r * 65 + kq + i * 4 + 2] = d.z;
                sX[r * 65 + kq + i * 4 + 3] = d.w;
            }
        }
        __syncthreads();
        int rg = tid >> 4;              // 0..15
        int c0 = (tid & 15) * 4;        // 0..60
        #pragma unroll
        for (int v = 0; v < 4; ++v) {
            int r = rg * 4 + v;
            // strict ascending-k FMA chains, bias added AFTER the sum (matches x@W + b)
            float a0 = 0.f, a1 = 0.f, a2 = 0.f, a3 = 0.f;
            #pragma unroll 8
            for (int k = 0; k < 64; ++k) {
                float xv = sX[r * 65 + k];
                a0 = fmaf(xv, sW[k * 64 + c0 + 0], a0);
                a1 = fmaf(xv, sW[k * 64 + c0 + 1], a1);
                a2 = fmaf(xv, sW[k * 64 + c0 + 2], a2);
                a3 = fmaf(xv, sW[k * 64 + c0 + 3], a3);
            }
            a0 = __fadd_rn(a0, sB[c0 + 0]);
            a1 = __fadd_rn(a1, sB[c0 + 1]);
            a2 = __fadd_rn(a2, sB[c0 + 2]);
            a3 = __fadd_rn(a3, sB[c0 + 3]);
            *(float4*)&ob[(size_t)(rt * 64 + r) * 64 + c0] =
                make_float4(fmaxf(a0, 0.f), fmaxf(a1, 0.f), fmaxf(a2, 0.f), fmaxf(a3, 0.f));
        }
    }
}

// ---------------- per-timestep stage kernels (f32, canonical sequential-k FMA) ----------------
// STAGE 1: u = A@[xt|h]; ux = u[:,0:64]; hz = relu(u@Wz1); hr = relu(u@Wr1)
// STAGE 2: C = A@[hz|hr]; z = sig(C[:,0:64]@Wz2); r = sig(C[:,64:]@Wr2); rh = r*h
// STAGE 3: C = A@rh; hc = relu(ux@Wc1[0:64] + C@Wc1[64:128])
// STAGE 4: C = A@hc; c = tanh(C@Wc2); hn = z*h + (1-z)*c -> hf, out
template <int STAGE>
__global__ __launch_bounds__(256) void stage_kernel(
    const float* __restrict__ e, int t,
    const float* __restrict__ xp,
    const float* __restrict__ Wz1, const float* __restrict__ Wz2,
    const float* __restrict__ Wr1, const float* __restrict__ Wr2,
    const float* __restrict__ Wc1, const float* __restrict__ Wc2,
    float* __restrict__ hf, float* __restrict__ ux,
    float* __restrict__ hz, float* __restrict__ hr,
    float* __restrict__ zb, float* __restrict__ rh,
    float* __restrict__ hc, float* __restrict__ out)
{
    constexpr int F  = (STAGE <= 2) ? 128 : 64;
    constexpr int BM = 16;
    constexpr int SA = 68;
    constexpr int SC = F + 4;
    constexpr int CT = (F == 128) ? 2 : 1;
    constexpr int SMEM = BM * SA + F * SA + BM * SC;
    __shared__ __align__(16) float smem[SMEM];
    float* sA  = smem;
    float* sVT = smem + BM * SA;
    float* sC  = smem + BM * SA + F * SA;
    float* sW  = smem;   // epilogue reuse of sA+sVT region; sC untouched

    const int b   = blockIdx.y;
    const int m0  = blockIdx.x * BM;
    const int tid = threadIdx.x;

    const float* Ab = e + ((size_t)(b * T_ + t) * N_ + m0) * N_;

    const float* v0;
    const float* v1 = nullptr;
    if (STAGE == 1)      { v0 = xp + (size_t)(b * T_ + t) * N_ * 64; v1 = hf + (size_t)b * N_ * 64; }
    else if (STAGE == 2) { v0 = hz + (size_t)b * N_ * 64;            v1 = hr + (size_t)b * N_ * 64; }
    else if (STAGE == 3) { v0 = rh + (size_t)b * N_ * 64; }
    else                 { v0 = hc + (size_t)b * N_ * 64; }

    const int r0 = (tid & 3) * 4;        // 4 rows per thread
    const int c0 = (tid >> 2) * CT;      // feature base
    float acc[4][CT];
    #pragma unroll
    for (int ri = 0; ri < 4; ++ri)
        #pragma unroll
        for (int ci = 0; ci < CT; ++ci) acc[ri][ci] = 0.f;

    for (int kb = 0; kb < N_; kb += 64) {
        {   // stage A tile [16][64]
            int r = tid >> 4, kq = (tid & 15) * 4;
            int sw = ((r >> 2) & 3) << 2;
            *(float4*)&sA[r * SA + (kq ^ sw)] = *(const float4*)(Ab + (size_t)r * N_ + kb + kq);
        }
        {   // stage V^T tile [F][64]
            #pragma unroll
            for (int pp = 0; pp < (64 * F) / 1024; ++pp) {
                int idx = pp * 1024 + tid * 4;
                int k = idx / F;
                int f = idx % F;
                const float* src;
                if constexpr (F == 128)
                    src = (f < 64) ? (v0 + (size_t)(kb + k) * 64 + f)
                                   : (v1 + (size_t)(kb + k) * 64 + (f - 64));
                else
                    src = v0 + (size_t)(kb + k) * 64 + f;
                float4 d4 = *(const float4*)src;
                float dd[4] = {d4.x, d4.y, d4.z, d4.w};
                #pragma unroll
                for (int j = 0; j < 4; ++j) {
                    int ff = f + j;
                    int sw = (((ff >> 3) ^ (ff >> 5)) & 3) << 2;
                    sVT[ff * SA + (k ^ sw)] = dd[j];
                }
            }
        }
        __syncthreads();
        #pragma unroll 4
        for (int k = 0; k < 64; k += 4) {
            float4 a4[4], v4[CT];
            #pragma unroll
            for (int ri = 0; ri < 4; ++ri) {
                int r = r0 + ri;
                a4[ri] = *(const float4*)&sA[r * SA + (k ^ (((r >> 2) & 3) << 2))];
            }
            #pragma unroll
            for (int ci = 0; ci < CT; ++ci) {
                int f = c0 + ci;
                v4[ci] = *(const float4*)&sVT[f * SA + (k ^ ((((f >> 3) ^ (f >> 5)) & 3) << 2))];
            }
            // strict ascending-k sequential FMA chain per output element
            #pragma unroll
            for (int ri = 0; ri < 4; ++ri)
                #pragma unroll
                for (int ci = 0; ci < CT; ++ci) {
                    acc[ri][ci] = fmaf(a4[ri].x, v4[ci].x, acc[ri][ci]);
                    acc[ri][ci] = fmaf(a4[ri].y, v4[ci].y, acc[ri][ci]);
                    acc[ri][ci] = fmaf(a4[ri].z, v4[ci].z, acc[ri][ci]);
                    acc[ri][ci] = fmaf(a4[ri].w, v4[ci].w, acc[ri][ci]);
                }
        }
        __syncthreads();
    }

    // STAGE 1: write ux = C[:,0:64] directly from registers
    if (STAGE == 1 && c0 < 64) {
        #pragma unroll
        for (int ri = 0; ri < 4; ++ri)
            *(float2*)&ux[((size_t)b * N_ + m0 + r0 + ri) * 64 + c0] =
                make_float2(acc[ri][0], acc[ri][1]);
    }

    // spill C to LDS
    #pragma unroll
    for (int ri = 0; ri < 4; ++ri) {
        if constexpr (CT == 2)
            *(float2*)&sC[(r0 + ri) * SC + c0] = make_float2(acc[ri][0], acc[ri][1]);
        else
            sC[(r0 + ri) * SC + c0] = acc[ri][0];
    }
    __syncthreads();

    const int rr  = tid >> 4;           // 0..15
    const int cc0 = (tid & 15) * 4;     // 0..60
    const float* Crow = &sC[rr * SC];
    const size_t orow = ((size_t)b * N_ + m0 + rr) * 64 + cc0;

    auto stageW = [&](const float* W, int n) {
        for (int i = tid * 4; i < n; i += 1024)
            *(float4*)&sW[i] = *(const float4*)&W[i];
    };

    if constexpr (STAGE == 1) {
        stageW(Wz1, 128 * 64); __syncthreads();
        float d[4] = {0.f, 0.f, 0.f, 0.f};
        for (int k = 0; k < 128; ++k) {
            float cv = Crow[k];
            const float* w = &sW[k * 64 + cc0];
            d[0] = fmaf(cv, w[0], d[0]); d[1] = fmaf(cv, w[1], d[1]);
            d[2] = fmaf(cv, w[2], d[2]); d[3] = fmaf(cv, w[3], d[3]);
        }
        *(float4*)&hz[orow] = make_float4(fmaxf(d[0], 0.f), fmaxf(d[1], 0.f),
                                          fmaxf(d[2], 0.f), fmaxf(d[3], 0.f));
        __syncthreads();
        stageW(Wr1, 128 * 64); __syncthreads();
        float g[4] = {0.f, 0.f, 0.f, 0.f};
        for (int k = 0; k < 128; ++k) {
            float cv = Crow[k];
            const float* w = &sW[k * 64 + cc0];
            g[0] = fmaf(cv, w[0], g[0]); g[1] = fmaf(cv, w[1], g[1]);
            g[2] = fmaf(cv, w[2], g[2]); g[3] = fmaf(cv, w[3], g[3]);
        }
        *(float4*)&hr[orow] = make_float4(fmaxf(g[0], 0.f), fmaxf(g[1], 0.f),
                                          fmaxf(g[2], 0.f), fmaxf(g[3], 0.f));
    }

    if constexpr (STAGE == 2) {
        stageW(Wz2, 64 * 64); __syncthreads();
        float d[4] = {0.f, 0.f, 0.f, 0.f};
        for (int k = 0; k < 64; ++k) {
            float cv = Crow[k];
            const float* w = &sW[k * 64 + cc0];
            d[0] = fmaf(cv, w[0], d[0]); d[1] = fmaf(cv, w[1], d[1]);
            d[2] = fmaf(cv, w[2], d[2]); d[3] = fmaf(cv, w[3], d[3]);
        }
        *(float4*)&zb[orow] = make_float4(fsig(d[0]), fsig(d[1]), fsig(d[2]), fsig(d[3]));
        __syncthreads();
        stageW(Wr2, 64 * 64); __syncthreads();
        float g[4] = {0.f, 0.f, 0.f, 0.f};
        for (int k = 0; k < 64; ++k) {
            float cv = Crow[64 + k];
            const float* w = &sW[k * 64 + cc0];
            g[0] = fmaf(cv, w[0], g[0]); g[1] = fmaf(cv, w[1], g[1]);
            g[2] = fmaf(cv, w[2], g[2]); g[3] = fmaf(cv, w[3], g[3]);
        }
        float4 hv = *(const float4*)&hf[orow];
        *(float4*)&rh[orow] = make_float4(__fmul_rn(fsig(g[0]), hv.x),
                                          __fmul_rn(fsig(g[1]), hv.y),
                                          __fmul_rn(fsig(g[2]), hv.z),
                                          __fmul_rn(fsig(g[3]), hv.w));
    }

    if constexpr (STAGE == 3) {
        stageW(Wc1, 64 * 64); __syncthreads();
        float d[4] = {0.f, 0.f, 0.f, 0.f};
        const float* uxr = &ux[((size_t)b * N_ + m0 + rr) * 64];
        for (int k = 0; k < 64; ++k) {
            float cv = uxr[k];
            const float* w = &sW[k * 64 + cc0];
            d[0] = fmaf(cv, w[0], d[0]); d[1] = fmaf(cv, w[1], d[1]);
            d[2] = fmaf(cv, w[2], d[2]); d[3] = fmaf(cv, w[3], d[3]);
        }
        __syncthreads();
        stageW(Wc1 + 64 * 64, 64 * 64); __syncthreads();
        for (int k = 0; k < 64; ++k) {
            float cv = Crow[k];
            const float* w = &sW[k * 64 + cc0];
            d[0] = fmaf(cv, w[0], d[0]); d[1] = fmaf(cv, w[1], d[1]);
            d[2] = fmaf(cv, w[2], d[2]); d[3] = fmaf(cv, w[3], d[3]);
        }
        *(float4*)&hc[orow] = make_float4(fmaxf(d[0], 0.f), fmaxf(d[1], 0.f),
                                          fmaxf(d[2], 0.f), fmaxf(d[3], 0.f));
    }

    if constexpr (STAGE == 4) {
        stageW(Wc2, 64 * 64); __syncthreads();
        float d[4] = {0.f, 0.f, 0.f, 0.f};
        for (int k = 0; k < 64; ++k) {
            float cv = Crow[k];
            const float* w = &sW[k * 64 + cc0];
            d[0] = fmaf(cv, w[0], d[0]); d[1] = fmaf(cv, w[1], d[1]);
            d[2] = fmaf(cv, w[2], d[2]); d[3] = fmaf(cv, w[3], d[3]);
        }
        float4 zv = *(const float4*)&zb[orow];
        float4 hv = *(const float4*)&hf[orow];
        float cg[4] = {ftanh(d[0]), ftanh(d[1]), ftanh(d[2]), ftanh(d[3])};
        float zz[4] = {zv.x, zv.y, zv.z, zv.w};
        float hh[4] = {hv.x, hv.y, hv.z, hv.w};
        float hn[4];
        #pragma unroll
        for (int j = 0; j < 4; ++j) {
            // z*h + (1-z)*c, elementwise non-contracted (matches array semantics)
            float t1 = __fmul_rn(zz[j], hh[j]);
            float om = __fsub_rn(1.0f, zz[j]);
            float t2 = __fmul_rn(om, cg[j]);
            hn[j] = __fadd_rn(t1, t2);
        }
        *(float4*)&hf[orow] = make_float4(hn[0], hn[1], hn[2], hn[3]);
        *(float4*)&out[((size_t)(b * T_ + t) * N_ + m0 + rr) * 64 + cc0] =
            make_float4(hn[0], hn[1], hn[2], hn[3]);
    }
    (void)v1;
}

extern "C" void kernel_launch(void* const* d_in, const int* in_sizes, int n_in,
                              void* d_out, int out_size, void* d_ws, size_t ws_size,
                              hipStream_t stream) {
    (void)in_sizes; (void)n_in; (void)out_size; (void)ws_size;
    const float* x    = (const float*)d_in[0];
    const float* e    = (const float*)d_in[1];
    const float* fc_w = (const float*)d_in[2];
    const float* fc_b = (const float*)d_in[3];
    const float* Wz1  = (const float*)d_in[4];
    const float* Wz2  = (const float*)d_in[5];
    const float* Wr1  = (const float*)d_in[6];
    const float* Wr2  = (const float*)d_in[7];
    const float* Wc1  = (const float*)d_in[8];
    const float* Wc2  = (const float*)d_in[9];
    float* out = (float*)d_out;

    char* p = (char*)d_ws;
    auto alloc = [&](size_t bytes) { char* r = p; p += (bytes + 255) & ~(size_t)255; return r; };
    float* xp = (float*)alloc((size_t)B_ * T_ * N_ * 64 * 4);
    float* hf = (float*)alloc((size_t)B_ * N_ * 64 * 4);
    float* ux = (float*)alloc((size_t)B_ * N_ * 64 * 4);
    float* hz = (float*)alloc((size_t)B_ * N_ * 64 * 4);
    float* hr = (float*)alloc((size_t)B_ * N_ * 64 * 4);
    float* zb = (float*)alloc((size_t)B_ * N_ * 64 * 4);
    float* rh = (float*)alloc((size_t)B_ * N_ * 64 * 4);
    float* hc = (float*)alloc((size_t)B_ * N_ * 64 * 4);

    hipMemsetAsync(hf, 0, (size_t)B_ * N_ * 64 * 4, stream);

    xp_kernel<<<dim3(B_ * T_), 256, 0, stream>>>(x, fc_w, fc_b, xp);

    dim3 grid(N_ / 16, B_);
    for (int t = 0; t < T_; ++t) {
        stage_kernel<1><<<grid, 256, 0, stream>>>(e, t, xp, Wz1, Wz2, Wr1, Wr2, Wc1, Wc2,
                                                  hf, ux, hz, hr, zb, rh, hc, out);
        stage_kernel<2><<<grid, 256, 0, stream>>>(e, t, xp, Wz1, Wz2, Wr1, Wr2, Wc1, Wc2,
                                                  hf, ux, hz, hr, zb, rh, hc, out);
        stage_kernel<3><<<grid, 256, 0, stream>>>(e, t, xp, Wz1, Wz2, Wr1, Wr2, Wc1, Wc2,
                                                  hf, ux, hz, hr, zb, rh, hc, out);
        stage_kernel<4><<<grid, 256, 0, stream>>>(e, t, xp, Wz1, Wz2, Wr1, Wr2, Wc1, Wc2,
                                                  hf, ux, hz, hr, zb, rh, hc, out);
    }
}